// Round 1
// baseline (1659.086 us; speedup 1.0000x reference)
//
#include <hip/hip_runtime.h>

#define N_NODES 50000
#define E_EDGES 800000
#define IN_DIM  256
#define HID     128
#define HALF    64
#define OUT_DIM 2
#define NB      16        // nodes per block (50000/16 = 3125 exactly)
#define SLOPE   0.01f

// ---------------------------------------------------------------- degree ----
__global__ void deg_init_kernel(float* __restrict__ degf) {
    int i = blockIdx.x * blockDim.x + threadIdx.x;
    if (i < N_NODES) degf[i] = 1.0f;   // self loop contributes 1 to target degree
}

__global__ void deg_count_kernel(const int* __restrict__ col, float* __restrict__ degf) {
    int e = blockIdx.x * blockDim.x + threadIdx.x;
    if (e < E_EDGES) atomicAdd(&degf[col[e]], 1.0f);
}

// ------------------------------------------------------------- node phase ---
// Per node i:
//   h      = leaky_relu(x[i] @ W_in + b_in)                  (256 -> 128)
//   x_nor  = h[:64]  @ W_nor   + b_nor                       (64  -> 128)
//   x_abnor= h[64:]  @ W_abnor + b_abnor                     (64  -> 128)
//   t      = tanh((x_nor + x_abnor) @ W_att + b_att)         (128 -> 128)
//   alpha  = sigmoid(t . v_att)                              (scalar per node!)
//   u[i]   = rsqrt(deg[i]) * (alpha*x_nor + (1-alpha)*x_abnor)
// u doubles as the self-loop init of the scatter accumulator.
__global__ __launch_bounds__(128) void node_phase_kernel(
    const float* __restrict__ x,
    const float* __restrict__ W_in,    const float* __restrict__ b_in,
    const float* __restrict__ W_nor,   const float* __restrict__ b_nor,
    const float* __restrict__ W_abnor, const float* __restrict__ b_abnor,
    const float* __restrict__ W_att,   const float* __restrict__ b_att,
    const float* __restrict__ v_att,
    const float* __restrict__ degf,
    float* __restrict__ u, float* __restrict__ acc)
{
    __shared__ float xs[NB][IN_DIM];   // 16 KB
    __shared__ float hs[NB][HID];      // 8 KB
    __shared__ float red[NB][HID];     // 8 KB (s, then t*v partials)

    const int c     = threadIdx.x;     // output channel 0..127
    const int node0 = blockIdx.x * NB;

    // stage 16 x-rows (coalesced)
    for (int idx = c; idx < NB * IN_DIM; idx += 128) {
        int n = idx >> 8, k = idx & (IN_DIM - 1);
        xs[n][k] = x[(size_t)(node0 + n) * IN_DIM + k];
    }
    __syncthreads();

    // h = leaky_relu(x @ W_in + b_in)
    float a[NB];
    {
        float bi = b_in[c];
        #pragma unroll
        for (int n = 0; n < NB; n++) a[n] = bi;
    }
    for (int k = 0; k < IN_DIM; k += 4) {
        float w0 = W_in[(k + 0) * HID + c];
        float w1 = W_in[(k + 1) * HID + c];
        float w2 = W_in[(k + 2) * HID + c];
        float w3 = W_in[(k + 3) * HID + c];
        #pragma unroll
        for (int n = 0; n < NB; n++) {
            float4 xv = *(const float4*)&xs[n][k];   // ds_read_b128 broadcast
            a[n] = fmaf(xv.x, w0, a[n]);
            a[n] = fmaf(xv.y, w1, a[n]);
            a[n] = fmaf(xv.z, w2, a[n]);
            a[n] = fmaf(xv.w, w3, a[n]);
        }
    }
    #pragma unroll
    for (int n = 0; n < NB; n++) {
        float v = a[n];
        hs[n][c] = v > 0.f ? v : SLOPE * v;
    }
    __syncthreads();

    // x_nor / x_abnor from the two halves of h
    float xn[NB], xa[NB];
    {
        float bn = b_nor[c], ba = b_abnor[c];
        #pragma unroll
        for (int n = 0; n < NB; n++) { xn[n] = bn; xa[n] = ba; }
    }
    for (int k = 0; k < HALF; k += 4) {
        float wn0 = W_nor[(k + 0) * HID + c],  wa0 = W_abnor[(k + 0) * HID + c];
        float wn1 = W_nor[(k + 1) * HID + c],  wa1 = W_abnor[(k + 1) * HID + c];
        float wn2 = W_nor[(k + 2) * HID + c],  wa2 = W_abnor[(k + 2) * HID + c];
        float wn3 = W_nor[(k + 3) * HID + c],  wa3 = W_abnor[(k + 3) * HID + c];
        #pragma unroll
        for (int n = 0; n < NB; n++) {
            float4 hlo = *(const float4*)&hs[n][k];
            float4 hhi = *(const float4*)&hs[n][HALF + k];
            xn[n] = fmaf(hlo.x, wn0, xn[n]);  xa[n] = fmaf(hhi.x, wa0, xa[n]);
            xn[n] = fmaf(hlo.y, wn1, xn[n]);  xa[n] = fmaf(hhi.y, wa1, xa[n]);
            xn[n] = fmaf(hlo.z, wn2, xn[n]);  xa[n] = fmaf(hhi.z, wa2, xa[n]);
            xn[n] = fmaf(hlo.w, wn3, xn[n]);  xa[n] = fmaf(hhi.w, wa3, xa[n]);
        }
    }
    // s = x_nor + x_abnor -> LDS
    #pragma unroll
    for (int n = 0; n < NB; n++) red[n][c] = xn[n] + xa[n];
    __syncthreads();

    // t = s @ W_att + b_att
    float t[NB];
    {
        float bt = b_att[c];
        #pragma unroll
        for (int n = 0; n < NB; n++) t[n] = bt;
    }
    for (int k = 0; k < HID; k += 4) {
        float w0 = W_att[(k + 0) * HID + c];
        float w1 = W_att[(k + 1) * HID + c];
        float w2 = W_att[(k + 2) * HID + c];
        float w3 = W_att[(k + 3) * HID + c];
        #pragma unroll
        for (int n = 0; n < NB; n++) {
            float4 sv = *(const float4*)&red[n][k];
            t[n] = fmaf(sv.x, w0, t[n]);
            t[n] = fmaf(sv.y, w1, t[n]);
            t[n] = fmaf(sv.z, w2, t[n]);
            t[n] = fmaf(sv.w, w3, t[n]);
        }
    }
    __syncthreads();   // done reading red as 's'

    // tanh(t) * v_att -> reduce over channels for alpha
    {
        float vv = v_att[c];
        #pragma unroll
        for (int n = 0; n < NB; n++) red[n][c] = tanhf(t[n]) * vv;
    }
    __syncthreads();
    for (int off = 64; off >= 1; off >>= 1) {
        if (c < off) {
            #pragma unroll
            for (int n = 0; n < NB; n++) red[n][c] += red[n][c + off];
        }
        __syncthreads();
    }

    #pragma unroll
    for (int n = 0; n < NB; n++) {
        float alpha = 1.f / (1.f + expf(-red[n][0]));
        float dinv  = rsqrtf(degf[node0 + n]);      // deg >= 1 always (self loop)
        float m     = alpha * xn[n] + (1.f - alpha) * xa[n];
        float uv    = dinv * m;
        size_t o    = (size_t)(node0 + n) * HID + c;
        u[o]   = uv;
        acc[o] = uv;   // self-loop term: aggr_i gets dinv_i * u_i
    }
}

// ------------------------------------------------------------- edge phase ---
// acc[col] += u[row] for every real edge (32 lanes/edge, float4 per lane)
__global__ __launch_bounds__(256) void edge_scatter_kernel(
    const int* __restrict__ ei, const float* __restrict__ u, float* __restrict__ acc)
{
    int gid = blockIdx.x * 256 + threadIdx.x;
    int e   = gid >> 5;
    if (e >= E_EDGES) return;
    int lane = gid & 31;
    int j = ei[e];             // row = source
    int i = ei[E_EDGES + e];   // col = target
    float4 v = *(const float4*)(u + (size_t)j * HID + lane * 4);
    float* dst = acc + (size_t)i * HID + lane * 4;
    atomicAdd(dst + 0, v.x);
    atomicAdd(dst + 1, v.y);
    atomicAdd(dst + 2, v.z);
    atomicAdd(dst + 3, v.w);
}

// ------------------------------------------------------------ final phase ---
// aggr = dinv * acc ; out = leaky_relu(aggr @ W_upd + b_upd) @ W_cls + b_cls
__global__ __launch_bounds__(128) void final_phase_kernel(
    const float* __restrict__ acc, const float* __restrict__ degf,
    const float* __restrict__ W_upd, const float* __restrict__ b_upd,
    const float* __restrict__ W_cls, const float* __restrict__ b_cls,
    float* __restrict__ out)
{
    __shared__ float as[NB][HID];
    __shared__ float us[NB][HID];
    const int c     = threadIdx.x;
    const int node0 = blockIdx.x * NB;

    #pragma unroll
    for (int n = 0; n < NB; n++) {
        int node = node0 + n;
        float d  = rsqrtf(degf[node]);
        as[n][c] = acc[(size_t)node * HID + c] * d;
    }
    __syncthreads();

    float up[NB];
    {
        float bu = b_upd[c];
        #pragma unroll
        for (int n = 0; n < NB; n++) up[n] = bu;
    }
    for (int k = 0; k < HID; k += 4) {
        float w0 = W_upd[(k + 0) * HID + c];
        float w1 = W_upd[(k + 1) * HID + c];
        float w2 = W_upd[(k + 2) * HID + c];
        float w3 = W_upd[(k + 3) * HID + c];
        #pragma unroll
        for (int n = 0; n < NB; n++) {
            float4 av = *(const float4*)&as[n][k];
            up[n] = fmaf(av.x, w0, up[n]);
            up[n] = fmaf(av.y, w1, up[n]);
            up[n] = fmaf(av.z, w2, up[n]);
            up[n] = fmaf(av.w, w3, up[n]);
        }
    }
    #pragma unroll
    for (int n = 0; n < NB; n++) {
        float v = up[n];
        us[n][c] = v > 0.f ? v : SLOPE * v;
    }
    __syncthreads();

    if (c < NB * OUT_DIM) {
        int n = c >> 1, o = c & 1;
        float s = b_cls[o];
        for (int k = 0; k < HID; k++)
            s = fmaf(us[n][k], W_cls[k * OUT_DIM + o], s);
        out[(size_t)(node0 + n) * OUT_DIM + o] = s;
    }
}

// ------------------------------------------------------------------ launch --
extern "C" void kernel_launch(void* const* d_in, const int* in_sizes, int n_in,
                              void* d_out, int out_size, void* d_ws, size_t ws_size,
                              hipStream_t stream)
{
    const float* x       = (const float*)d_in[0];
    const int*   ei      = (const int*)  d_in[1];   // [2, E] int32 (JAX x64 off)
    const float* W_in    = (const float*)d_in[2];
    const float* b_in    = (const float*)d_in[3];
    const float* W_nor   = (const float*)d_in[4];
    const float* b_nor   = (const float*)d_in[5];
    const float* W_abnor = (const float*)d_in[6];
    const float* b_abnor = (const float*)d_in[7];
    const float* W_att   = (const float*)d_in[8];
    const float* b_att   = (const float*)d_in[9];
    const float* v_att   = (const float*)d_in[10];
    const float* W_upd   = (const float*)d_in[11];
    const float* b_upd   = (const float*)d_in[12];
    const float* W_cls   = (const float*)d_in[13];
    const float* b_cls   = (const float*)d_in[14];
    float* out = (float*)d_out;

    // workspace: degf [N] | u [N*HID] | acc [N*HID]  (~51.6 MB)
    float* degf = (float*)d_ws;
    float* u    = degf + N_NODES;
    float* acc  = u + (size_t)N_NODES * HID;

    deg_init_kernel <<<(N_NODES + 255) / 256, 256, 0, stream>>>(degf);
    deg_count_kernel<<<(E_EDGES + 255) / 256, 256, 0, stream>>>(ei + E_EDGES, degf);
    node_phase_kernel<<<N_NODES / NB, 128, 0, stream>>>(
        x, W_in, b_in, W_nor, b_nor, W_abnor, b_abnor,
        W_att, b_att, v_att, degf, u, acc);
    edge_scatter_kernel<<<((size_t)E_EDGES * 32 + 255) / 256, 256, 0, stream>>>(ei, u, acc);
    final_phase_kernel<<<N_NODES / NB, 128, 0, stream>>>(
        acc, degf, W_upd, b_upd, W_cls, b_cls, out);
}

// Round 2
// 520.223 us; speedup vs baseline: 3.1892x; 3.1892x over previous
//
#include <hip/hip_runtime.h>

#define N_NODES 50000
#define E_EDGES 800000
#define IN_DIM  256
#define HID     128
#define HALF    64
#define OUT_DIM 2
#define NB      16        // nodes per block (50000/16 = 3125 exactly)
#define SLOPE   0.01f

// ---------------------------------------------------------------- degree ----
__global__ void zero_int_kernel(int* __restrict__ p, int n) {
    int i = blockIdx.x * blockDim.x + threadIdx.x;
    if (i < n) p[i] = 0;
}

__global__ void deg_count_kernel(const int* __restrict__ col, int* __restrict__ cnt) {
    int e = blockIdx.x * blockDim.x + threadIdx.x;
    if (e < E_EDGES) atomicAdd(&cnt[col[e]], 1);
}

// Exclusive scan of cnt[0..N) -> row_start[0..N], single 1024-thread block.
__global__ __launch_bounds__(1024) void scan_kernel(
    const int* __restrict__ cnt, int* __restrict__ row_start)
{
    __shared__ int sums[1024];
    const int T  = 1024;
    const int t  = threadIdx.x;
    const int CH = (N_NODES + T - 1) / T;   // 49
    const int base = t * CH;

    int s = 0;
    for (int k = 0; k < CH; k++) {
        int i = base + k;
        if (i < N_NODES) s += cnt[i];
    }
    sums[t] = s;
    __syncthreads();
    // Hillis-Steele inclusive scan over 1024 thread-totals
    for (int off = 1; off < T; off <<= 1) {
        int v = (t >= off) ? sums[t - off] : 0;
        __syncthreads();
        sums[t] += v;
        __syncthreads();
    }
    int run = (t == 0) ? 0 : sums[t - 1];
    for (int k = 0; k < CH; k++) {
        int i = base + k;
        if (i < N_NODES) { row_start[i] = run; run += cnt[i]; }
    }
    if (t == T - 1) row_start[N_NODES] = run;
}

__global__ void fill_kernel(const int* __restrict__ ei,
                            const int* __restrict__ row_start,
                            int* __restrict__ cursor, int* __restrict__ csr_src)
{
    int e = blockIdx.x * blockDim.x + threadIdx.x;
    if (e >= E_EDGES) return;
    int j = ei[e];              // source
    int i = ei[E_EDGES + e];    // target
    int pos = row_start[i] + atomicAdd(&cursor[i], 1);
    csr_src[pos] = j;
}

// ------------------------------------------------------------- node phase ---
// Per node i (alpha is a scalar per SOURCE node -> edge matmuls collapse):
//   h      = leaky_relu(x[i] @ W_in + b_in)
//   x_nor  = h[:64] @ W_nor + b_nor ;  x_abnor = h[64:] @ W_abnor + b_abnor
//   alpha  = sigmoid(tanh((x_nor+x_abnor) @ W_att + b_att) . v_att)
//   u[i]   = rsqrt(deg[i]) * (alpha*x_nor + (1-alpha)*x_abnor)
__global__ __launch_bounds__(128) void node_phase_kernel(
    const float* __restrict__ x,
    const float* __restrict__ W_in,    const float* __restrict__ b_in,
    const float* __restrict__ W_nor,   const float* __restrict__ b_nor,
    const float* __restrict__ W_abnor, const float* __restrict__ b_abnor,
    const float* __restrict__ W_att,   const float* __restrict__ b_att,
    const float* __restrict__ v_att,
    const int* __restrict__ cnt,
    float* __restrict__ u)
{
    __shared__ float xs[NB][IN_DIM];   // 16 KB
    __shared__ float hs[NB][HID];      // 8 KB
    __shared__ float red[NB][HID];     // 8 KB (s, then t*v partials)

    const int c     = threadIdx.x;     // output channel 0..127
    const int node0 = blockIdx.x * NB;

    for (int idx = c; idx < NB * IN_DIM; idx += 128) {
        int n = idx >> 8, k = idx & (IN_DIM - 1);
        xs[n][k] = x[(size_t)(node0 + n) * IN_DIM + k];
    }
    __syncthreads();

    float a[NB];
    {
        float bi = b_in[c];
        #pragma unroll
        for (int n = 0; n < NB; n++) a[n] = bi;
    }
    for (int k = 0; k < IN_DIM; k += 4) {
        float w0 = W_in[(k + 0) * HID + c];
        float w1 = W_in[(k + 1) * HID + c];
        float w2 = W_in[(k + 2) * HID + c];
        float w3 = W_in[(k + 3) * HID + c];
        #pragma unroll
        for (int n = 0; n < NB; n++) {
            float4 xv = *(const float4*)&xs[n][k];
            a[n] = fmaf(xv.x, w0, a[n]);
            a[n] = fmaf(xv.y, w1, a[n]);
            a[n] = fmaf(xv.z, w2, a[n]);
            a[n] = fmaf(xv.w, w3, a[n]);
        }
    }
    #pragma unroll
    for (int n = 0; n < NB; n++) {
        float v = a[n];
        hs[n][c] = v > 0.f ? v : SLOPE * v;
    }
    __syncthreads();

    float xn[NB], xa[NB];
    {
        float bn = b_nor[c], ba = b_abnor[c];
        #pragma unroll
        for (int n = 0; n < NB; n++) { xn[n] = bn; xa[n] = ba; }
    }
    for (int k = 0; k < HALF; k += 4) {
        float wn0 = W_nor[(k + 0) * HID + c],  wa0 = W_abnor[(k + 0) * HID + c];
        float wn1 = W_nor[(k + 1) * HID + c],  wa1 = W_abnor[(k + 1) * HID + c];
        float wn2 = W_nor[(k + 2) * HID + c],  wa2 = W_abnor[(k + 2) * HID + c];
        float wn3 = W_nor[(k + 3) * HID + c],  wa3 = W_abnor[(k + 3) * HID + c];
        #pragma unroll
        for (int n = 0; n < NB; n++) {
            float4 hlo = *(const float4*)&hs[n][k];
            float4 hhi = *(const float4*)&hs[n][HALF + k];
            xn[n] = fmaf(hlo.x, wn0, xn[n]);  xa[n] = fmaf(hhi.x, wa0, xa[n]);
            xn[n] = fmaf(hlo.y, wn1, xn[n]);  xa[n] = fmaf(hhi.y, wa1, xa[n]);
            xn[n] = fmaf(hlo.z, wn2, xn[n]);  xa[n] = fmaf(hhi.z, wa2, xa[n]);
            xn[n] = fmaf(hlo.w, wn3, xn[n]);  xa[n] = fmaf(hhi.w, wa3, xa[n]);
        }
    }
    #pragma unroll
    for (int n = 0; n < NB; n++) red[n][c] = xn[n] + xa[n];
    __syncthreads();

    float t[NB];
    {
        float bt = b_att[c];
        #pragma unroll
        for (int n = 0; n < NB; n++) t[n] = bt;
    }
    for (int k = 0; k < HID; k += 4) {
        float w0 = W_att[(k + 0) * HID + c];
        float w1 = W_att[(k + 1) * HID + c];
        float w2 = W_att[(k + 2) * HID + c];
        float w3 = W_att[(k + 3) * HID + c];
        #pragma unroll
        for (int n = 0; n < NB; n++) {
            float4 sv = *(const float4*)&red[n][k];
            t[n] = fmaf(sv.x, w0, t[n]);
            t[n] = fmaf(sv.y, w1, t[n]);
            t[n] = fmaf(sv.z, w2, t[n]);
            t[n] = fmaf(sv.w, w3, t[n]);
        }
    }
    __syncthreads();

    {
        float vv = v_att[c];
        #pragma unroll
        for (int n = 0; n < NB; n++) red[n][c] = tanhf(t[n]) * vv;
    }
    __syncthreads();
    for (int off = 64; off >= 1; off >>= 1) {
        if (c < off) {
            #pragma unroll
            for (int n = 0; n < NB; n++) red[n][c] += red[n][c + off];
        }
        __syncthreads();
    }

    #pragma unroll
    for (int n = 0; n < NB; n++) {
        float alpha = 1.f / (1.f + expf(-red[n][0]));
        float dinv  = rsqrtf((float)cnt[node0 + n] + 1.0f);  // +1 self loop
        float m     = alpha * xn[n] + (1.f - alpha) * xa[n];
        u[(size_t)(node0 + n) * HID + c] = dinv * m;
    }
}

// ------------------------------------------------------------- edge phase ---
// One wave (64 lanes) per target node: acc[i] = u[i] + sum_{j in in(i)} u[j]
__global__ __launch_bounds__(256) void gather_kernel(
    const int* __restrict__ row_start, const int* __restrict__ csr_src,
    const float* __restrict__ u, float* __restrict__ acc)
{
    int node = blockIdx.x * 4 + (threadIdx.x >> 6);
    int lane = threadIdx.x & 63;
    if (node >= N_NODES) return;

    const float* up = u + (size_t)node * HID + lane * 2;
    float2 s = *(const float2*)up;                   // self loop: dinv_i * u_i handled later
    int b = row_start[node], e = row_start[node + 1];
    for (int p = b; p < e; p++) {
        int j = csr_src[p];
        float2 v = *(const float2*)(u + (size_t)j * HID + lane * 2);
        s.x += v.x; s.y += v.y;
    }
    *(float2*)(acc + (size_t)node * HID + lane * 2) = s;
}

// ------------------------------------------------------------ final phase ---
__global__ __launch_bounds__(128) void final_phase_kernel(
    const float* __restrict__ acc, const int* __restrict__ cnt,
    const float* __restrict__ W_upd, const float* __restrict__ b_upd,
    const float* __restrict__ W_cls, const float* __restrict__ b_cls,
    float* __restrict__ out)
{
    __shared__ float as[NB][HID];
    __shared__ float us[NB][HID];
    const int c     = threadIdx.x;
    const int node0 = blockIdx.x * NB;

    #pragma unroll
    for (int n = 0; n < NB; n++) {
        int node = node0 + n;
        float d  = rsqrtf((float)cnt[node] + 1.0f);
        as[n][c] = acc[(size_t)node * HID + c] * d;
    }
    __syncthreads();

    float up[NB];
    {
        float bu = b_upd[c];
        #pragma unroll
        for (int n = 0; n < NB; n++) up[n] = bu;
    }
    for (int k = 0; k < HID; k += 4) {
        float w0 = W_upd[(k + 0) * HID + c];
        float w1 = W_upd[(k + 1) * HID + c];
        float w2 = W_upd[(k + 2) * HID + c];
        float w3 = W_upd[(k + 3) * HID + c];
        #pragma unroll
        for (int n = 0; n < NB; n++) {
            float4 av = *(const float4*)&as[n][k];
            up[n] = fmaf(av.x, w0, up[n]);
            up[n] = fmaf(av.y, w1, up[n]);
            up[n] = fmaf(av.z, w2, up[n]);
            up[n] = fmaf(av.w, w3, up[n]);
        }
    }
    #pragma unroll
    for (int n = 0; n < NB; n++) {
        float v = up[n];
        us[n][c] = v > 0.f ? v : SLOPE * v;
    }
    __syncthreads();

    if (c < NB * OUT_DIM) {
        int n = c >> 1, o = c & 1;
        float s = b_cls[o];
        for (int k = 0; k < HID; k++)
            s = fmaf(us[n][k], W_cls[k * OUT_DIM + o], s);
        out[(size_t)(node0 + n) * OUT_DIM + o] = s;
    }
}

// ------------------------------------------------------------------ launch --
extern "C" void kernel_launch(void* const* d_in, const int* in_sizes, int n_in,
                              void* d_out, int out_size, void* d_ws, size_t ws_size,
                              hipStream_t stream)
{
    const float* x       = (const float*)d_in[0];
    const int*   ei      = (const int*)  d_in[1];   // [2, E] int32
    const float* W_in    = (const float*)d_in[2];
    const float* b_in    = (const float*)d_in[3];
    const float* W_nor   = (const float*)d_in[4];
    const float* b_nor   = (const float*)d_in[5];
    const float* W_abnor = (const float*)d_in[6];
    const float* b_abnor = (const float*)d_in[7];
    const float* W_att   = (const float*)d_in[8];
    const float* b_att   = (const float*)d_in[9];
    const float* v_att   = (const float*)d_in[10];
    const float* W_upd   = (const float*)d_in[11];
    const float* b_upd   = (const float*)d_in[12];
    const float* W_cls   = (const float*)d_in[13];
    const float* b_cls   = (const float*)d_in[14];
    float* out = (float*)d_out;

    // workspace layout (ints then floats):
    // cnt[N] | cursor[N] | row_start[N+1] | csr_src[E] | u[N*HID] | acc[N*HID]
    int*   cnt       = (int*)d_ws;
    int*   cursor    = cnt + N_NODES;
    int*   row_start = cursor + N_NODES;
    int*   csr_src   = row_start + (N_NODES + 1);
    float* u         = (float*)(csr_src + E_EDGES);
    float* acc       = u + (size_t)N_NODES * HID;

    zero_int_kernel<<<(2 * N_NODES + 255) / 256, 256, 0, stream>>>(cnt, 2 * N_NODES);
    deg_count_kernel<<<(E_EDGES + 255) / 256, 256, 0, stream>>>(ei + E_EDGES, cnt);
    scan_kernel<<<1, 1024, 0, stream>>>(cnt, row_start);
    fill_kernel<<<(E_EDGES + 255) / 256, 256, 0, stream>>>(ei, row_start, cursor, csr_src);
    node_phase_kernel<<<N_NODES / NB, 128, 0, stream>>>(
        x, W_in, b_in, W_nor, b_nor, W_abnor, b_abnor,
        W_att, b_att, v_att, cnt, u);
    gather_kernel<<<(N_NODES + 3) / 4, 256, 0, stream>>>(row_start, csr_src, u, acc);
    final_phase_kernel<<<N_NODES / NB, 128, 0, stream>>>(
        acc, cnt, W_upd, b_upd, W_cls, b_cls, out);
}